// Round 14
// baseline (31.951 us; speedup 1.0000x reference)
//
#include <hip/hip_runtime.h>

#define OUT_N 5
#define TOTAL_NODES 65024
#define ROOTS_OFF (TOTAL_NODES * OUT_N)

typedef __attribute__((ext_vector_type(8))) short bf16x8;
typedef __attribute__((ext_vector_type(4))) float f32x4;
typedef __attribute__((ext_vector_type(8))) unsigned short ushort8v;
typedef __attribute__((ext_vector_type(4))) unsigned int uint4v;

constexpr int B_BYTES = 137216;                  // 67*2*64*16
constexpr int NODE_SZ = 16128;                   // 126 rows * 128 B fp32
constexpr int LEAF_SZ = 8192;                    // 128 rows * 64 B bf16
constexpr int NODE = B_BYTES;
constexpr int LEAF = NODE + NODE_SZ;
constexpr int SCR  = LEAF;                       // scratch aliases dead leaves
constexpr int LDS_BIG = B_BYTES + NODE_SZ + LEAF_SZ;   // 161536

static __device__ __forceinline__ float bf2f(unsigned short u) {
    union { unsigned int i; float f; } v; v.i = ((unsigned int)u) << 16; return v.f;
}
static __device__ __forceinline__ unsigned short f2bf(float f) {
    union { float f; unsigned int i; } v; v.f = f;
    unsigned int r = v.i + 0x7fff + ((v.i >> 16) & 1);   // RNE
    return (unsigned short)(r >> 16);
}

// fp32 node row R (128 B): chunk rotated by R+(R>>1) (<=2-way conflicts, free)
static __device__ __forceinline__ int naddr32(int R, int c) {
    return R * 128 + (((c + R + (R >> 1)) & 7) << 4);
}
// bf16 leaf row R (64 B): 16B chunk rotated
static __device__ __forceinline__ int laddr16(int R, int q) {
    return R * 64 + (((q + R + (R >> 1)) & 3) << 4);
}
static __device__ __forceinline__ void store_h32(char* base, int R, int col, float v) {
    *(float*)(base + naddr32(R, col >> 2) + (col & 3) * 4) = v;
}
static __device__ __forceinline__ void load_crot32(
    const char* base, int Rc, int hi, float* crot)
{
    #pragma unroll
    for (int t = 0; t < 16; ++t) {
        int m = (hi * 2 + t) & 15;
        f32x4 v = *(const f32x4*)(base + naddr32(Rc + (m >> 3), m & 7));
        #pragma unroll
        for (int e = 0; e < 4; ++e) crot[t * 4 + e] = v[e];
    }
}

// ---------------------------------------------------------------------------
// bprep: block per k (32 blocks). Stage V[k] (16 KB) into LDS COALESCED,
// then compute fragments from LDS (round-13 gather was 16 scattered 4B
// loads/lane). Output layout identical to round 13.
// ---------------------------------------------------------------------------
__global__ __launch_bounds__(256) void bprep_kernel(
    const float* __restrict__ V, const float* __restrict__ W,
    unsigned short* __restrict__ B)
{
    __shared__ float vk[4096];
    const int tid = threadIdx.x, k = blockIdx.x;
    #pragma unroll
    for (int i = 0; i < 4; ++i) {
        int idx = i * 256 + tid;
        ((f32x4*)vk)[idx] = ((const f32x4*)(V + (size_t)k * 4096))[idx];
    }
    __syncthreads();
    const int n = k >> 4, l15 = k & 15;
    for (int jb = tid; jb < 268; jb += 256) {
        int ks = jb % 67, hi4 = jb / 67;
        ushort8v o;
        #pragma unroll
        for (int i = 0; i < 8; ++i) {
            int r5 = hi4 * 8 + i;
            float val;
            if (ks < 2)        { int j = 32 * ks + r5; val = vk[j * 64 + j]; }
            else if (ks < 64)  { int d = ks >> 1; int j = 32 * (ks & 1) + r5;
                                 int l = (j + d) & 63;
                                 val = vk[j * 64 + l] + vk[l * 64 + j]; }
            else if (ks == 64) { int j = r5; val = vk[j * 64 + j + 32] + vk[(j + 32) * 64 + j]; }
            else               { int j = (ks == 65) ? r5 : (32 + r5); val = W[j * 32 + k]; }
            o[i] = f2bf(val);
        }
        *(ushort8v*)(B + (size_t)(ks * 128 + n * 64 + hi4 * 16 + l15) * 8) = o;
    }
}

// ---------------------------------------------------------------------------
// Single-ntile compile-time K-range; B from LDS at offset 0.
// ---------------------------------------------------------------------------
template<int K0, int K1>
static __device__ __forceinline__ f32x4 run1(
    const float* crot, int lane, int n, f32x4 acc)
{
    extern __shared__ char smem[];
    const int lo = lane * 16 + (n << 10);
    #pragma unroll
    for (int ks = K0; ks < K1; ++ks) {
        uint4v aw;
        #pragma unroll
        for (int q = 0; q < 4; ++q) {
            int i0 = 2 * q, i1 = 2 * q + 1;
            float p0, p1;
            if (ks < 2)       { p0 = crot[32*ks+i0] * crot[32*ks+i0];
                                p1 = crot[32*ks+i1] * crot[32*ks+i1]; }
            else if (ks < 64) { const int bse = 32 * (ks & 1), d = ks >> 1;
                                p0 = crot[bse+i0] * crot[(bse+i0+d)&63];
                                p1 = crot[bse+i1] * crot[(bse+i1+d)&63]; }
            else if (ks == 64){ p0 = crot[i0] * crot[32+i0];
                                p1 = crot[i1] * crot[32+i1]; }
            else if (ks == 65){ p0 = crot[i0];    p1 = crot[i1]; }
            else              { p0 = crot[32+i0]; p1 = crot[32+i1]; }
            unsigned int pk;
            asm("v_cvt_pk_bf16_f32 %0, %1, %2" : "=v"(pk) : "v"(p0), "v"(p1));
            aw[q] = pk;
        }
        bf16x8 afr = __builtin_bit_cast(bf16x8, aw);
        bf16x8 b = *(const bf16x8*)(smem + (ks << 11) + lo);
        acc = __builtin_amdgcn_mfma_f32_16x16x32_bf16(afr, b, acc, 0, 0, 0);
    }
    return acc;
}

// log_softmax from fp32 node LDS row -> out[g*5..]
static __device__ __forceinline__ void node_logits32(
    const char* nodebase, int R, const float* __restrict__ Wout_w,
    const float* __restrict__ Wout_b, float* __restrict__ out, size_t g)
{
    float h[32];
    #pragma unroll
    for (int c = 0; c < 8; ++c) {
        f32x4 v = *(const f32x4*)(nodebase + naddr32(R, c));
        #pragma unroll
        for (int e = 0; e < 4; ++e) h[c * 4 + e] = v[e];
    }
    float lg[OUT_N];
    #pragma unroll
    for (int o = 0; o < OUT_N; ++o) {
        const float* ww = Wout_w + o * 32;
        float s = 0.f;
        #pragma unroll
        for (int x = 0; x < 32; ++x) s = fmaf(ww[x], h[x], s);
        lg[o] = s + Wout_b[o];
    }
    float m = lg[0];
    #pragma unroll
    for (int o = 1; o < OUT_N; ++o) m = fmaxf(m, lg[o]);
    float sum = 0.f;
    #pragma unroll
    for (int o = 0; o < OUT_N; ++o) sum += expf(lg[o] - m);
    float lse = m + logf(sum);
    #pragma unroll
    for (int o = 0; o < OUT_N; ++o) out[g * OUT_N + o] = lg[o] - lse;
}

// ---------------------------------------------------------------------------
// L1: ALL 16 waves busy. 4 tiles (tree,half) x 2 ntiles x splitK2.
// crot from bf16 leaves; slots (8 x 1KB fp32) alias leaf region AFTER the
// crot-load barrier. L1 wall: 67 -> 34 ksteps.
// ---------------------------------------------------------------------------
static __device__ __attribute__((noinline)) void worker_l1(
    const float* __restrict__ bias, int tid)
{
    extern __shared__ char smem[];
    const int lane = tid & 63, w = tid >> 6;
    const int l15 = lane & 15, hi = lane >> 4;
    const int t = w >> 2, n = (w >> 1) & 1, u = w & 1;
    const int tree = t >> 1, half = t & 1;

    const int Rc = tree * 64 + half * 32 + 2 * l15;
    float crot[64];
    #pragma unroll
    for (int tt = 0; tt < 8; ++tt) {
        int m = (hi + tt) & 7;
        ushort8v v = *(const ushort8v*)(smem + LEAF + laddr16(Rc + (m >> 2), m & 3));
        #pragma unroll
        for (int e = 0; e < 8; ++e) crot[tt * 8 + e] = bf2f(v[e]);
    }
    __syncthreads();                         // leaf region -> scratch handoff

    f32x4 a = {0.f,0.f,0.f,0.f};
    if (u == 0) a = run1< 0, 34>(crot, lane, n, a);
    else        a = run1<34, 67>(crot, lane, n, a);

    if (u == 1) *(f32x4*)(smem + SCR + ((t * 2 + n) << 10) + lane * 16) = a;
    __syncthreads();
    if (u == 0) {
        a += *(const f32x4*)(smem + SCR + ((t * 2 + n) << 10) + lane * 16);
        float bk = bias[n * 16 + l15];
        #pragma unroll
        for (int r = 0; r < 4; ++r) {
            int R = tree * 63 + half * 16 + hi * 4 + r;
            store_h32(smem + NODE, R, n * 16 + l15, tanhf(a[r] + bk));
        }
    }
    __syncthreads();
}

// ---------------------------------------------------------------------------
// L2: waves 0..7 (tree2 x ntile2 x splitK2), round-13-identical math.
// ---------------------------------------------------------------------------
static __device__ __attribute__((noinline)) void worker_l2(
    const float* __restrict__ bias, int tid)
{
    extern __shared__ char smem[];
    const int lane = tid & 63, w = tid >> 6;
    const int l15 = lane & 15, hi = lane >> 4;
    const int tree = (w >> 2) & 1, n = (w >> 1) & 1, u = w & 1;

    f32x4 a = {0.f,0.f,0.f,0.f};
    if (w < 8) {
        float crot[64];
        load_crot32(smem + NODE, tree * 63 + 2 * l15, hi, crot);
        if (u == 0) a = run1< 0, 34>(crot, lane, n, a);
        else        a = run1<34, 67>(crot, lane, n, a);
        if (u == 1) *(f32x4*)(smem + SCR + ((tree * 2 + n) << 10) + lane * 16) = a;
    }
    __syncthreads();
    if (w < 8 && u == 0) {
        a += *(const f32x4*)(smem + SCR + ((tree * 2 + n) << 10) + lane * 16);
        float bk = bias[n * 16 + l15];
        #pragma unroll
        for (int r = 0; r < 4; ++r) {
            int R = tree * 63 + 32 + hi * 4 + r;
            store_h32(smem + NODE, R, n * 16 + l15, tanhf(a[r] + bk));
        }
    }
    __syncthreads();
}

// ---------------------------------------------------------------------------
// L3..L6: waves 0..7 (ntile2 x splitK4), packed 2-tree tile. r13-identical.
// ---------------------------------------------------------------------------
static __device__ __attribute__((noinline)) void worker_deep(
    const float* __restrict__ bias, float* __restrict__ roots,
    int bid, int tid, int s, int childb, int outb, bool root)
{
    extern __shared__ char smem[];
    const int lane = tid & 63, w = tid >> 6;
    const int l15 = lane & 15, hi = lane >> 4;
    const int n = (w >> 2) & 1, u = w & 3;
    const int rptT = 1 << s, rows2 = 2 << s;

    f32x4 a = {0.f,0.f,0.f,0.f};
    if (w < 8) {
        int rc = (l15 < rows2) ? l15 : 0;
        int tree = rc >> s, i = rc & (rptT - 1);
        float crot[64];
        load_crot32(smem + NODE, tree * 63 + childb + 2 * i, hi, crot);
        switch (u) {
            case 0:  a = run1< 0, 17>(crot, lane, n, a); break;
            case 1:  a = run1<17, 34>(crot, lane, n, a); break;
            case 2:  a = run1<34, 50>(crot, lane, n, a); break;
            default: a = run1<50, 67>(crot, lane, n, a); break;
        }
        if (u > 0) *(f32x4*)(smem + SCR + ((n * 3 + u - 1) << 10) + lane * 16) = a;
    }
    __syncthreads();
    if (w < 8 && u == 0) {
        #pragma unroll
        for (int v2 = 0; v2 < 3; ++v2)
            a += *(const f32x4*)(smem + SCR + ((n * 3 + v2) << 10) + lane * 16);
        float bk = bias[n * 16 + l15];
        #pragma unroll
        for (int r = 0; r < 4; ++r) {
            int row = hi * 4 + r;
            if (row < rows2) {
                int t2 = row >> s, i2 = row & (rptT - 1);
                float h = tanhf(a[r] + bk);
                store_h32(smem + NODE, t2 * 63 + outb + i2, n * 16 + l15, h);
                if (root) roots[(size_t)(bid * 2 + t2) * 32 + n * 16 + l15] = h;
            }
        }
    }
    __syncthreads();
}

// ---------------------------------------------------------------------------
// Fused tree kernel: block = 2 trees, 256 blocks x 1024 thr (16 waves,
// 4 waves/SIMD). B staged to LDS once; nodes fp32; leaves bf16.
// ---------------------------------------------------------------------------
__global__ __launch_bounds__(1024, 2) void tree_kernel(
    const int* __restrict__ word_ids, const float* __restrict__ embed,
    const unsigned short* __restrict__ Bg, const float* __restrict__ bias,
    const float* __restrict__ Wout_w, const float* __restrict__ Wout_b,
    float* __restrict__ out)
{
    extern __shared__ char smem[];
    const int tid = threadIdx.x, bid = blockIdx.x;
    float* roots = out + ROOTS_OFF;

    // ---- stage B into LDS (137 KB, coalesced 16B/thread) ------------------
    {
        const ushort8v* src = (const ushort8v*)Bg;
        #pragma unroll
        for (int r2 = 0; r2 < 8; ++r2) {
            int idx = r2 * 1024 + tid;
            *(ushort8v*)(smem + idx * 16) = src[idx];
        }
        int idx = 8192 + tid;
        if (idx < 8576) *(ushort8v*)(smem + idx * 16) = src[idx];
    }

    // ---- stage 128 leaf rows (bf16) + EXACT fp32 leaf logits --------------
    {
        int rr = tid >> 3, q4 = tid & 7;         // 8 thr/row x 4 floats
        int leaf = bid * 128 + rr;
        int wid = word_ids[leaf];
        f32x4 v = ((const f32x4*)(embed + (size_t)wid * 32))[q4];
        uint2 st;
        st.x = (unsigned)f2bf(v[0]) | ((unsigned)f2bf(v[1]) << 16);
        st.y = (unsigned)f2bf(v[2]) | ((unsigned)f2bf(v[3]) << 16);
        *(uint2*)(smem + LEAF + laddr16(rr, q4 >> 1) + (q4 & 1) * 8) = st;

        float lg[OUT_N];
        #pragma unroll
        for (int o5 = 0; o5 < OUT_N; ++o5) {
            const float* ww = Wout_w + o5 * 32 + q4 * 4;
            lg[o5] = ww[0]*v[0] + ww[1]*v[1] + ww[2]*v[2] + ww[3]*v[3];
        }
        #pragma unroll
        for (int o5 = 0; o5 < OUT_N; ++o5) {
            lg[o5] += __shfl_xor(lg[o5], 1, 64);
            lg[o5] += __shfl_xor(lg[o5], 2, 64);
            lg[o5] += __shfl_xor(lg[o5], 4, 64);
        }
        if (q4 == 0) {
            #pragma unroll
            for (int o5 = 0; o5 < OUT_N; ++o5) lg[o5] += Wout_b[o5];
            float m = lg[0];
            #pragma unroll
            for (int o5 = 1; o5 < OUT_N; ++o5) m = fmaxf(m, lg[o5]);
            float sum = 0.f;
            #pragma unroll
            for (int o5 = 0; o5 < OUT_N; ++o5) sum += expf(lg[o5] - m);
            float lse = m + logf(sum);
            #pragma unroll
            for (int o5 = 0; o5 < OUT_N; ++o5)
                out[(size_t)leaf * OUT_N + o5] = lg[o5] - lse;
        }
    }
    __syncthreads();

    // ---- 6 levels ---------------------------------------------------------
    worker_l1(bias, tid);
    worker_l2(bias, tid);
    worker_deep(bias, roots, bid, tid, 3, 32, 48, false);  // L3
    worker_deep(bias, roots, bid, tid, 2, 48, 56, false);  // L4
    worker_deep(bias, roots, bid, tid, 1, 56, 60, false);  // L5
    worker_deep(bias, roots, bid, tid, 0, 60, 62, true);   // L6

    // ---- logits for 126 internal rows (2 trees x 63) ----------------------
    if (tid < 126) {
        int tree = (tid >= 63) ? 1 : 0;
        int r = tid - 63 * tree;
        size_t tg = (size_t)bid * 2 + tree;
        int R = tree * 63 + r;
        size_t g;
        if (r < 32)      g = 32768 + tg * 32 + r;
        else if (r < 48) g = 49152 + tg * 16 + (r - 32);
        else if (r < 56) g = 57344 + tg * 8  + (r - 48);
        else if (r < 60) g = 61440 + tg * 4  + (r - 56);
        else if (r < 62) g = 63488 + tg * 2  + (r - 60);
        else             g = 64512 + tg;
        node_logits32(smem + NODE, R, Wout_w, Wout_b, out, g);
    }
}

// ---------------------------------------------------------------------------
extern "C" void kernel_launch(void* const* d_in, const int* in_sizes, int n_in,
                              void* d_out, int out_size, void* d_ws, size_t ws_size,
                              hipStream_t stream)
{
    const int*   word_ids = (const int*)  d_in[0];
    const float* embed    = (const float*)d_in[1];
    const float* V        = (const float*)d_in[2];
    const float* W        = (const float*)d_in[3];
    const float* bvec     = (const float*)d_in[4];
    const float* Wout_w   = (const float*)d_in[5];
    const float* Wout_b   = (const float*)d_in[6];
    float* out = (float*)d_out;

    unsigned short* Bfrag = (unsigned short*)d_ws;   // 137,216 B

    bprep_kernel<<<32, 256, 0, stream>>>(V, W, Bfrag);

    (void)hipFuncSetAttribute((const void*)&tree_kernel,
            hipFuncAttributeMaxDynamicSharedMemorySize, LDS_BIG);
    tree_kernel<<<256, 1024, LDS_BIG, stream>>>(
        word_ids, embed, Bfrag, bvec, Wout_w, Wout_b, out);
}

// Round 16
// 31.424 us; speedup vs baseline: 1.0168x; 1.0168x over previous
//
#include <hip/hip_runtime.h>

#define OUT_N 5
#define TOTAL_NODES 65024
#define ROOTS_OFF (TOTAL_NODES * OUT_N)

typedef __attribute__((ext_vector_type(8))) short bf16x8;
typedef __attribute__((ext_vector_type(4))) float f32x4;
typedef __attribute__((ext_vector_type(8))) unsigned short ushort8v;
typedef __attribute__((ext_vector_type(4))) unsigned int uint4v;

constexpr int B_BYTES   = 137216;                 // 67*2*64*16
constexpr int NODE_SZ   = 16128;                  // 126 rows * 128 B fp32
constexpr int LEAF_SZ   = 8192;                   // 128 rows * 64 B bf16
constexpr int LDS_BIG   = B_BYTES + NODE_SZ + LEAF_SZ;   // 161536
constexpr int LDS_SMALL = NODE_SZ + LEAF_SZ;             // 24320

static __device__ __forceinline__ float bf2f(unsigned short u) {
    union { unsigned int i; float f; } v; v.i = ((unsigned int)u) << 16; return v.f;
}
static __device__ __forceinline__ unsigned short f2bf(float f) {
    union { float f; unsigned int i; } v; v.f = f;
    unsigned int r = v.i + 0x7fff + ((v.i >> 16) & 1);   // RNE
    return (unsigned short)(r >> 16);
}

// fp32 internal row R (128 B): chunk rotated by R+(R>>1) (<=2-way, free m136)
static __device__ __forceinline__ int naddr32(int R, int c) {
    return R * 128 + (((c + R + (R >> 1)) & 7) << 4);
}
// bf16 leaf row R (64 B): 16B chunk rotated the same way (4 chunks).
static __device__ __forceinline__ int laddr16(int R, int q) {
    return R * 64 + (((q + R + (R >> 1)) & 3) << 4);
}
static __device__ __forceinline__ void store_h32(char* base, int R, int col, float v) {
    *(float*)(base + naddr32(R, col >> 2) + (col & 3) * 4) = v;
}
static __device__ __forceinline__ void load_crot32(
    const char* base, int Rc, int hi, float* crot)
{
    #pragma unroll
    for (int t = 0; t < 16; ++t) {
        int m = (hi * 2 + t) & 15;
        f32x4 v = *(const f32x4*)(base + naddr32(Rc + (m >> 3), m & 7));
        #pragma unroll
        for (int e = 0; e < 4; ++e) crot[t * 4 + e] = v[e];
    }
}

// ---------------------------------------------------------------------------
// bprep (r14-proven): block per k; V[k] staged COALESCED into LDS, fragments
// computed from LDS. Output layout identical to r13.
// ---------------------------------------------------------------------------
__global__ __launch_bounds__(256) void bprep_kernel(
    const float* __restrict__ V, const float* __restrict__ W,
    unsigned short* __restrict__ B)
{
    __shared__ float vk[4096];
    const int tid = threadIdx.x, k = blockIdx.x;
    #pragma unroll
    for (int i = 0; i < 4; ++i) {
        int idx = i * 256 + tid;
        ((f32x4*)vk)[idx] = ((const f32x4*)(V + (size_t)k * 4096))[idx];
    }
    __syncthreads();
    const int n = k >> 4, l15 = k & 15;
    for (int jb = tid; jb < 268; jb += 256) {
        int ks = jb % 67, hi4 = jb / 67;
        ushort8v o;
        #pragma unroll
        for (int i = 0; i < 8; ++i) {
            int r5 = hi4 * 8 + i;
            float val;
            if (ks < 2)        { int j = 32 * ks + r5; val = vk[j * 64 + j]; }
            else if (ks < 64)  { int d = ks >> 1; int j = 32 * (ks & 1) + r5;
                                 int l = (j + d) & 63;
                                 val = vk[j * 64 + l] + vk[l * 64 + j]; }
            else if (ks == 64) { int j = r5; val = vk[j * 64 + j + 32] + vk[(j + 32) * 64 + j]; }
            else               { int j = (ks == 65) ? r5 : (32 + r5); val = W[j * 32 + k]; }
            o[i] = f2bf(val);
        }
        *(ushort8v*)(B + (size_t)(ks * 128 + n * 64 + hi4 * 16 + l15) * 8) = o;
    }
}

// ---------------------------------------------------------------------------
// Single-ntile K-range: A built in fp32 from crot (compile-time indices),
// B from LDS (BLDS=1) or global (fallback).
// ---------------------------------------------------------------------------
template<int BLDS, int K0, int K1>
static __device__ __forceinline__ f32x4 run1(
    const unsigned short* __restrict__ Bg, const float* crot,
    int lane, int n, f32x4 acc)
{
    extern __shared__ char smem[];
    const int lo = lane * 16 + (n << 10);
    #pragma unroll
    for (int ks = K0; ks < K1; ++ks) {
        uint4v aw;
        #pragma unroll
        for (int q = 0; q < 4; ++q) {
            int i0 = 2 * q, i1 = 2 * q + 1;
            float p0, p1;
            if (ks < 2)       { p0 = crot[32*ks+i0] * crot[32*ks+i0];
                                p1 = crot[32*ks+i1] * crot[32*ks+i1]; }
            else if (ks < 64) { const int bse = 32 * (ks & 1), d = ks >> 1;
                                p0 = crot[bse+i0] * crot[(bse+i0+d)&63];
                                p1 = crot[bse+i1] * crot[(bse+i1+d)&63]; }
            else if (ks == 64){ p0 = crot[i0] * crot[32+i0];
                                p1 = crot[i1] * crot[32+i1]; }
            else if (ks == 65){ p0 = crot[i0];    p1 = crot[i1]; }
            else              { p0 = crot[32+i0]; p1 = crot[32+i1]; }
            unsigned int pk;
            asm("v_cvt_pk_bf16_f32 %0, %1, %2" : "=v"(pk) : "v"(p0), "v"(p1));
            aw[q] = pk;
        }
        bf16x8 afr = __builtin_bit_cast(bf16x8, aw);
        bf16x8 b;
        if constexpr (BLDS) b = *(const bf16x8*)(smem + (ks << 11) + lo);
        else                b = *(const bf16x8*)((const char*)Bg + (ks << 11) + lo);
        acc = __builtin_amdgcn_mfma_f32_16x16x32_bf16(afr, b, acc, 0, 0, 0);
    }
    return acc;
}

// ---------------------------------------------------------------------------
// L1: 8 waves = 4 tiles x 2 ntiles, full K, NO reduction. bf16 leaf children.
// ---------------------------------------------------------------------------
template<int BLDS>
static __device__ __attribute__((noinline)) void worker_l1(
    const unsigned short* __restrict__ Bg, const float* __restrict__ bias, int tid)
{
    extern __shared__ char smem[];
    constexpr int NODE = BLDS ? B_BYTES : 0;
    constexpr int LEAF = NODE + NODE_SZ;
    const int lane = tid & 63, w = tid >> 6;
    const int l15 = lane & 15, hi = lane >> 4;
    const int tile = w >> 1, n = w & 1;
    const int tree = tile >> 1, half = tile & 1;

    const int Rc = tree * 64 + half * 32 + 2 * l15;   // leaf child-pair rows
    float crot[64];
    #pragma unroll
    for (int t = 0; t < 8; ++t) {
        int m = (hi + t) & 7;
        ushort8v v = *(const ushort8v*)(smem + LEAF + laddr16(Rc + (m >> 2), m & 3));
        #pragma unroll
        for (int e = 0; e < 8; ++e) crot[t * 8 + e] = bf2f(v[e]);
    }

    f32x4 a = {0.f,0.f,0.f,0.f};
    a = run1<BLDS, 0, 67>(Bg, crot, lane, n, a);

    float bk = bias[n * 16 + l15];
    #pragma unroll
    for (int r = 0; r < 4; ++r) {
        int R = tree * 63 + half * 16 + hi * 4 + r;
        store_h32(smem + NODE, R, n * 16 + l15, tanhf(a[r] + bk));
    }
    __syncthreads();
}

// ---------------------------------------------------------------------------
// L2: 8 waves = 2 trees x 2 ntiles x splitK2. fp32 h1 children.
// ---------------------------------------------------------------------------
template<int BLDS>
static __device__ __attribute__((noinline)) void worker_l2(
    const unsigned short* __restrict__ Bg, const float* __restrict__ bias, int tid)
{
    extern __shared__ char smem[];
    constexpr int NODE = BLDS ? B_BYTES : 0;
    constexpr int SCR  = NODE + NODE_SZ;     // aliases dead leaf region
    const int lane = tid & 63, w = tid >> 6;
    const int l15 = lane & 15, hi = lane >> 4;
    const int tree = w >> 2, n = (w >> 1) & 1, u = w & 1;

    float crot[64];
    load_crot32(smem + NODE, tree * 63 + 2 * l15, hi, crot);

    f32x4 a = {0.f,0.f,0.f,0.f};
    if (u == 0) a = run1<BLDS,  0, 34>(Bg, crot, lane, n, a);
    else        a = run1<BLDS, 34, 67>(Bg, crot, lane, n, a);

    if (u == 1) *(f32x4*)(smem + SCR + ((tree * 2 + n) << 10) + lane * 16) = a;
    __syncthreads();
    if (u == 0) {
        a += *(const f32x4*)(smem + SCR + ((tree * 2 + n) << 10) + lane * 16);
        float bk = bias[n * 16 + l15];
        #pragma unroll
        for (int r = 0; r < 4; ++r) {
            int R = tree * 63 + 32 + hi * 4 + r;
            store_h32(smem + NODE, R, n * 16 + l15, tanhf(a[r] + bk));
        }
    }
    __syncthreads();
}

// ---------------------------------------------------------------------------
// L3..L6: packed 2-tree tile, 8 waves = 2 ntiles x splitK4. s = log2(rows/tree).
// ---------------------------------------------------------------------------
template<int BLDS>
static __device__ __attribute__((noinline)) void worker_deep(
    const unsigned short* __restrict__ Bg, const float* __restrict__ bias,
    float* __restrict__ roots, int bid, int tid,
    int s, int childb, int outb, bool root)
{
    extern __shared__ char smem[];
    constexpr int NODE = BLDS ? B_BYTES : 0;
    constexpr int SCR  = NODE + NODE_SZ;
    const int lane = tid & 63, w = tid >> 6;
    const int l15 = lane & 15, hi = lane >> 4;
    const int n = w >> 2, u = w & 3;
    const int rptT = 1 << s, rows2 = 2 << s;

    int rc = (l15 < rows2) ? l15 : 0;
    int tree = rc >> s, i = rc & (rptT - 1);
    float crot[64];
    load_crot32(smem + NODE, tree * 63 + childb + 2 * i, hi, crot);

    f32x4 a = {0.f,0.f,0.f,0.f};
    switch (u) {
        case 0:  a = run1<BLDS,  0, 17>(Bg, crot, lane, n, a); break;
        case 1:  a = run1<BLDS, 17, 34>(Bg, crot, lane, n, a); break;
        case 2:  a = run1<BLDS, 34, 50>(Bg, crot, lane, n, a); break;
        default: a = run1<BLDS, 50, 67>(Bg, crot, lane, n, a); break;
    }
    if (u > 0) *(f32x4*)(smem + SCR + ((n * 3 + u - 1) << 10) + lane * 16) = a;
    __syncthreads();
    if (u == 0) {
        #pragma unroll
        for (int v2 = 0; v2 < 3; ++v2)
            a += *(const f32x4*)(smem + SCR + ((n * 3 + v2) << 10) + lane * 16);
        float bk = bias[n * 16 + l15];
        #pragma unroll
        for (int r = 0; r < 4; ++r) {
            int row = hi * 4 + r;
            if (row < rows2) {
                int t2 = row >> s, i2 = row & (rptT - 1);
                float h = tanhf(a[r] + bk);
                store_h32(smem + NODE, t2 * 63 + outb + i2, n * 16 + l15, h);
                if (root) roots[(size_t)(bid * 2 + t2) * 32 + n * 16 + l15] = h;
            }
        }
    }
    __syncthreads();
}

// log_softmax from fp32 internal LDS row -> out[g*5..]
static __device__ __forceinline__ void node_logits32(
    const char* nodebase, int R, const float* __restrict__ Wout_w,
    const float* __restrict__ Wout_b, float* __restrict__ out, size_t g)
{
    float h[32];
    #pragma unroll
    for (int c = 0; c < 8; ++c) {
        f32x4 v = *(const f32x4*)(nodebase + naddr32(R, c));
        #pragma unroll
        for (int e = 0; e < 4; ++e) h[c * 4 + e] = v[e];
    }
    float lg[OUT_N];
    #pragma unroll
    for (int o = 0; o < OUT_N; ++o) {
        const float* ww = Wout_w + o * 32;
        float s = 0.f;
        #pragma unroll
        for (int x = 0; x < 32; ++x) s = fmaf(ww[x], h[x], s);
        lg[o] = s + Wout_b[o];
    }
    float m = lg[0];
    #pragma unroll
    for (int o = 1; o < OUT_N; ++o) m = fmaxf(m, lg[o]);
    float sum = 0.f;
    #pragma unroll
    for (int o = 0; o < OUT_N; ++o) sum += expf(lg[o] - m);
    float lse = m + logf(sum);
    #pragma unroll
    for (int o = 0; o < OUT_N; ++o) out[g * OUT_N + o] = lg[o] - lse;
}

// ---------------------------------------------------------------------------
// Fused tree kernel (r13-proven): block = 2 trees, 256 blocks x 512 thr,
// 1 block/CU. B staged to LDS once; all kstep reads are ds_read.
// ---------------------------------------------------------------------------
template<int BLDS>
__global__ __launch_bounds__(512, 2) void tree_kernel(
    const int* __restrict__ word_ids, const float* __restrict__ embed,
    const unsigned short* __restrict__ Bg, const float* __restrict__ bias,
    const float* __restrict__ Wout_w, const float* __restrict__ Wout_b,
    float* __restrict__ out)
{
    extern __shared__ char smem[];
    constexpr int NODE = BLDS ? B_BYTES : 0;
    constexpr int LEAF = NODE + NODE_SZ;
    const int tid = threadIdx.x, bid = blockIdx.x;
    float* roots = out + ROOTS_OFF;

    // ---- stage B into LDS (137 KB, coalesced 16B/thread) ------------------
    if constexpr (BLDS) {
        const ushort8v* src = (const ushort8v*)Bg;
        #pragma unroll
        for (int r2 = 0; r2 < 16; ++r2) {
            int idx = r2 * 512 + tid;
            *(ushort8v*)(smem + idx * 16) = src[idx];
        }
        int idx = 8192 + tid;
        if (idx < 8576) *(ushort8v*)(smem + idx * 16) = src[idx];
    }

    // ---- stage 128 leaf rows (bf16) + EXACT fp32 leaf logits --------------
    {
        int rr = tid >> 2, q4 = tid & 3;         // 4 thr/row, 8 floats each
        int leaf = bid * 128 + rr;
        int wid = word_ids[leaf];
        const f32x4* ep = (const f32x4*)(embed + (size_t)wid * 32) + q4 * 2;
        f32x4 v0 = ep[0], v1 = ep[1];
        ushort8v o;
        #pragma unroll
        for (int e = 0; e < 4; ++e) { o[e] = f2bf(v0[e]); o[4 + e] = f2bf(v1[e]); }
        *(ushort8v*)(smem + LEAF + laddr16(rr, q4)) = o;

        float lg[OUT_N];
        #pragma unroll
        for (int o5 = 0; o5 < OUT_N; ++o5) {
            const float* ww = Wout_w + o5 * 32 + q4 * 8;
            lg[o5] = ww[0]*v0[0] + ww[1]*v0[1] + ww[2]*v0[2] + ww[3]*v0[3]
                   + ww[4]*v1[0] + ww[5]*v1[1] + ww[6]*v1[2] + ww[7]*v1[3];
        }
        #pragma unroll
        for (int o5 = 0; o5 < OUT_N; ++o5) {
            lg[o5] += __shfl_xor(lg[o5], 1, 64);
            lg[o5] += __shfl_xor(lg[o5], 2, 64);
        }
        if (q4 == 0) {
            #pragma unroll
            for (int o5 = 0; o5 < OUT_N; ++o5) lg[o5] += Wout_b[o5];
            float m = lg[0];
            #pragma unroll
            for (int o5 = 1; o5 < OUT_N; ++o5) m = fmaxf(m, lg[o5]);
            float sum = 0.f;
            #pragma unroll
            for (int o5 = 0; o5 < OUT_N; ++o5) sum += expf(lg[o5] - m);
            float lse = m + logf(sum);
            #pragma unroll
            for (int o5 = 0; o5 < OUT_N; ++o5)
                out[(size_t)leaf * OUT_N + o5] = lg[o5] - lse;
        }
    }
    __syncthreads();

    // ---- 6 levels ---------------------------------------------------------
    worker_l1<BLDS>(Bg, bias, tid);
    worker_l2<BLDS>(Bg, bias, tid);
    worker_deep<BLDS>(Bg, bias, roots, bid, tid, 3, 32, 48, false);  // L3
    worker_deep<BLDS>(Bg, bias, roots, bid, tid, 2, 48, 56, false);  // L4
    worker_deep<BLDS>(Bg, bias, roots, bid, tid, 1, 56, 60, false);  // L5
    worker_deep<BLDS>(Bg, bias, roots, bid, tid, 0, 60, 62, true);   // L6

    // ---- logits for 126 internal rows (2 trees x 63) ----------------------
    if (tid < 126) {
        int tree = (tid >= 63) ? 1 : 0;
        int r = tid - 63 * tree;
        size_t tg = (size_t)bid * 2 + tree;
        int R = tree * 63 + r;
        size_t g;
        if (r < 32)      g = 32768 + tg * 32 + r;
        else if (r < 48) g = 49152 + tg * 16 + (r - 32);
        else if (r < 56) g = 57344 + tg * 8  + (r - 48);
        else if (r < 60) g = 61440 + tg * 4  + (r - 56);
        else if (r < 62) g = 63488 + tg * 2  + (r - 60);
        else             g = 64512 + tg;
        node_logits32(smem + NODE, R, Wout_w, Wout_b, out, g);
    }
}

// ---------------------------------------------------------------------------
extern "C" void kernel_launch(void* const* d_in, const int* in_sizes, int n_in,
                              void* d_out, int out_size, void* d_ws, size_t ws_size,
                              hipStream_t stream)
{
    const int*   word_ids = (const int*)  d_in[0];
    const float* embed    = (const float*)d_in[1];
    const float* V        = (const float*)d_in[2];
    const float* W        = (const float*)d_in[3];
    const float* bvec     = (const float*)d_in[4];
    const float* Wout_w   = (const float*)d_in[5];
    const float* Wout_b   = (const float*)d_in[6];
    float* out = (float*)d_out;

    unsigned short* Bfrag = (unsigned short*)d_ws;   // 137,216 B

    bprep_kernel<<<32, 256, 0, stream>>>(V, W, Bfrag);

    hipError_t e = hipFuncSetAttribute((const void*)&tree_kernel<1>,
                     hipFuncAttributeMaxDynamicSharedMemorySize, LDS_BIG);
    if (e == hipSuccess) {
        tree_kernel<1><<<256, 512, LDS_BIG, stream>>>(
            word_ids, embed, Bfrag, bvec, Wout_w, Wout_b, out);
    } else {
        tree_kernel<0><<<256, 512, LDS_SMALL, stream>>>(
            word_ids, embed, Bfrag, bvec, Wout_w, Wout_b, out);
    }
}

// Round 18
// 31.411 us; speedup vs baseline: 1.0172x; 1.0004x over previous
//
#include <hip/hip_runtime.h>

#define OUT_N 5
#define TOTAL_NODES 65024
#define ROOTS_OFF (TOTAL_NODES * OUT_N)

typedef __attribute__((ext_vector_type(8))) short bf16x8;
typedef __attribute__((ext_vector_type(4))) float f32x4;
typedef __attribute__((ext_vector_type(8))) unsigned short ushort8v;
typedef __attribute__((ext_vector_type(4))) unsigned int uint4v;

constexpr int B_BYTES   = 137216;                 // 67*2*64*16
constexpr int NODE_SZ   = 16128;                  // 126 rows * 128 B fp32
constexpr int LEAF_SZ   = 8192;                   // 128 rows * 64 B bf16
constexpr int LDS_BIG   = B_BYTES + NODE_SZ + LEAF_SZ;   // 161536
constexpr int LDS_SMALL = NODE_SZ + LEAF_SZ;             // 24320

static __device__ __forceinline__ float bf2f(unsigned short u) {
    union { unsigned int i; float f; } v; v.i = ((unsigned int)u) << 16; return v.f;
}
static __device__ __forceinline__ unsigned short f2bf(float f) {
    union { float f; unsigned int i; } v; v.f = f;
    unsigned int r = v.i + 0x7fff + ((v.i >> 16) & 1);   // RNE
    return (unsigned short)(r >> 16);
}

// fp32 internal row R (128 B): chunk rotated by R+(R>>1) (<=2-way, free m136)
static __device__ __forceinline__ int naddr32(int R, int c) {
    return R * 128 + (((c + R + (R >> 1)) & 7) << 4);
}
// bf16 leaf row R (64 B): 16B chunk rotated the same way (4 chunks).
static __device__ __forceinline__ int laddr16(int R, int q) {
    return R * 64 + (((q + R + (R >> 1)) & 3) << 4);
}
static __device__ __forceinline__ void store_h32(char* base, int R, int col, float v) {
    *(float*)(base + naddr32(R, col >> 2) + (col & 3) * 4) = v;
}
static __device__ __forceinline__ void load_crot32(
    const char* base, int Rc, int hi, float* crot)
{
    #pragma unroll
    for (int t = 0; t < 16; ++t) {
        int m = (hi * 2 + t) & 15;
        f32x4 v = *(const f32x4*)(base + naddr32(Rc + (m >> 3), m & 7));
        #pragma unroll
        for (int e = 0; e < 4; ++e) crot[t * 4 + e] = v[e];
    }
}

// ---------------------------------------------------------------------------
// bprep (r14-proven): block per k; V[k] staged COALESCED into LDS, fragments
// computed from LDS.
// ---------------------------------------------------------------------------
__global__ __launch_bounds__(256) void bprep_kernel(
    const float* __restrict__ V, const float* __restrict__ W,
    unsigned short* __restrict__ B)
{
    __shared__ float vk[4096];
    const int tid = threadIdx.x, k = blockIdx.x;
    #pragma unroll
    for (int i = 0; i < 4; ++i) {
        int idx = i * 256 + tid;
        ((f32x4*)vk)[idx] = ((const f32x4*)(V + (size_t)k * 4096))[idx];
    }
    __syncthreads();
    const int n = k >> 4, l15 = k & 15;
    for (int jb = tid; jb < 268; jb += 256) {
        int ks = jb % 67, hi4 = jb / 67;
        ushort8v o;
        #pragma unroll
        for (int i = 0; i < 8; ++i) {
            int r5 = hi4 * 8 + i;
            float val;
            if (ks < 2)        { int j = 32 * ks + r5; val = vk[j * 64 + j]; }
            else if (ks < 64)  { int d = ks >> 1; int j = 32 * (ks & 1) + r5;
                                 int l = (j + d) & 63;
                                 val = vk[j * 64 + l] + vk[l * 64 + j]; }
            else if (ks == 64) { int j = r5; val = vk[j * 64 + j + 32] + vk[(j + 32) * 64 + j]; }
            else               { int j = (ks == 65) ? r5 : (32 + r5); val = W[j * 32 + k]; }
            o[i] = f2bf(val);
        }
        *(ushort8v*)(B + (size_t)(ks * 128 + n * 64 + hi4 * 16 + l15) * 8) = o;
    }
}

// ---------------------------------------------------------------------------
// Single-ntile K-range: A built in fp32 from crot (compile-time indices),
// B from LDS (BLDS=1) or global (fallback).
// ---------------------------------------------------------------------------
template<int BLDS, int K0, int K1>
static __device__ __forceinline__ f32x4 run1(
    const unsigned short* __restrict__ Bg, const float* crot,
    int lane, int n, f32x4 acc)
{
    extern __shared__ char smem[];
    const int lo = lane * 16 + (n << 10);
    #pragma unroll
    for (int ks = K0; ks < K1; ++ks) {
        uint4v aw;
        #pragma unroll
        for (int q = 0; q < 4; ++q) {
            int i0 = 2 * q, i1 = 2 * q + 1;
            float p0, p1;
            if (ks < 2)       { p0 = crot[32*ks+i0] * crot[32*ks+i0];
                                p1 = crot[32*ks+i1] * crot[32*ks+i1]; }
            else if (ks < 64) { const int bse = 32 * (ks & 1), d = ks >> 1;
                                p0 = crot[bse+i0] * crot[(bse+i0+d)&63];
                                p1 = crot[bse+i1] * crot[(bse+i1+d)&63]; }
            else if (ks == 64){ p0 = crot[i0] * crot[32+i0];
                                p1 = crot[i1] * crot[32+i1]; }
            else if (ks == 65){ p0 = crot[i0];    p1 = crot[i1]; }
            else              { p0 = crot[32+i0]; p1 = crot[32+i1]; }
            unsigned int pk;
            asm("v_cvt_pk_bf16_f32 %0, %1, %2" : "=v"(pk) : "v"(p0), "v"(p1));
            aw[q] = pk;
        }
        bf16x8 afr = __builtin_bit_cast(bf16x8, aw);
        bf16x8 b;
        if constexpr (BLDS) b = *(const bf16x8*)(smem + (ks << 11) + lo);
        else                b = *(const bf16x8*)((const char*)Bg + (ks << 11) + lo);
        acc = __builtin_amdgcn_mfma_f32_16x16x32_bf16(afr, b, acc, 0, 0, 0);
    }
    return acc;
}

// ---------------------------------------------------------------------------
// L1: 8 waves = 4 tiles x 2 ntiles, full K, NO reduction. bf16 leaf children.
// ---------------------------------------------------------------------------
template<int BLDS>
static __device__ __attribute__((noinline)) void worker_l1(
    const unsigned short* __restrict__ Bg, const float* __restrict__ bias, int tid)
{
    extern __shared__ char smem[];
    constexpr int NODE = BLDS ? B_BYTES : 0;
    constexpr int LEAF = NODE + NODE_SZ;
    const int lane = tid & 63, w = tid >> 6;
    const int l15 = lane & 15, hi = lane >> 4;
    const int tile = w >> 1, n = w & 1;
    const int tree = tile >> 1, half = tile & 1;

    const int Rc = tree * 64 + half * 32 + 2 * l15;   // leaf child-pair rows
    float crot[64];
    #pragma unroll
    for (int t = 0; t < 8; ++t) {
        int m = (hi + t) & 7;
        ushort8v v = *(const ushort8v*)(smem + LEAF + laddr16(Rc + (m >> 2), m & 3));
        #pragma unroll
        for (int e = 0; e < 8; ++e) crot[t * 8 + e] = bf2f(v[e]);
    }

    f32x4 a = {0.f,0.f,0.f,0.f};
    a = run1<BLDS, 0, 67>(Bg, crot, lane, n, a);

    float bk = bias[n * 16 + l15];
    #pragma unroll
    for (int r = 0; r < 4; ++r) {
        int R = tree * 63 + half * 16 + hi * 4 + r;
        store_h32(smem + NODE, R, n * 16 + l15, tanhf(a[r] + bk));
    }
    __syncthreads();
}

// ---------------------------------------------------------------------------
// L2: 8 waves = 2 trees x 2 ntiles x splitK2. fp32 h1 children.
// ---------------------------------------------------------------------------
template<int BLDS>
static __device__ __attribute__((noinline)) void worker_l2(
    const unsigned short* __restrict__ Bg, const float* __restrict__ bias, int tid)
{
    extern __shared__ char smem[];
    constexpr int NODE = BLDS ? B_BYTES : 0;
    constexpr int SCR  = NODE + NODE_SZ;     // aliases dead leaf region
    const int lane = tid & 63, w = tid >> 6;
    const int l15 = lane & 15, hi = lane >> 4;
    const int tree = w >> 2, n = (w >> 1) & 1, u = w & 1;

    float crot[64];
    load_crot32(smem + NODE, tree * 63 + 2 * l15, hi, crot);

    f32x4 a = {0.f,0.f,0.f,0.f};
    if (u == 0) a = run1<BLDS,  0, 34>(Bg, crot, lane, n, a);
    else        a = run1<BLDS, 34, 67>(Bg, crot, lane, n, a);

    if (u == 1) *(f32x4*)(smem + SCR + ((tree * 2 + n) << 10) + lane * 16) = a;
    __syncthreads();
    if (u == 0) {
        a += *(const f32x4*)(smem + SCR + ((tree * 2 + n) << 10) + lane * 16);
        float bk = bias[n * 16 + l15];
        #pragma unroll
        for (int r = 0; r < 4; ++r) {
            int R = tree * 63 + 32 + hi * 4 + r;
            store_h32(smem + NODE, R, n * 16 + l15, tanhf(a[r] + bk));
        }
    }
    __syncthreads();
}

// ---------------------------------------------------------------------------
// L3..L6: packed 2-tree tile, 8 waves = 2 ntiles x splitK4. s = log2(rows/tree).
// ---------------------------------------------------------------------------
template<int BLDS>
static __device__ __attribute__((noinline)) void worker_deep(
    const unsigned short* __restrict__ Bg, const float* __restrict__ bias,
    float* __restrict__ roots, int bid, int tid,
    int s, int childb, int outb, bool root)
{
    extern __shared__ char smem[];
    constexpr int NODE = BLDS ? B_BYTES : 0;
    constexpr int SCR  = NODE + NODE_SZ;
    const int lane = tid & 63, w = tid >> 6;
    const int l15 = lane & 15, hi = lane >> 4;
    const int n = w >> 2, u = w & 3;
    const int rptT = 1 << s, rows2 = 2 << s;

    int rc = (l15 < rows2) ? l15 : 0;
    int tree = rc >> s, i = rc & (rptT - 1);
    float crot[64];
    load_crot32(smem + NODE, tree * 63 + childb + 2 * i, hi, crot);

    f32x4 a = {0.f,0.f,0.f,0.f};
    switch (u) {
        case 0:  a = run1<BLDS,  0, 17>(Bg, crot, lane, n, a); break;
        case 1:  a = run1<BLDS, 17, 34>(Bg, crot, lane, n, a); break;
        case 2:  a = run1<BLDS, 34, 50>(Bg, crot, lane, n, a); break;
        default: a = run1<BLDS, 50, 67>(Bg, crot, lane, n, a); break;
    }
    if (u > 0) *(f32x4*)(smem + SCR + ((n * 3 + u - 1) << 10) + lane * 16) = a;
    __syncthreads();
    if (u == 0) {
        #pragma unroll
        for (int v2 = 0; v2 < 3; ++v2)
            a += *(const f32x4*)(smem + SCR + ((n * 3 + v2) << 10) + lane * 16);
        float bk = bias[n * 16 + l15];
        #pragma unroll
        for (int r = 0; r < 4; ++r) {
            int row = hi * 4 + r;
            if (row < rows2) {
                int t2 = row >> s, i2 = row & (rptT - 1);
                float h = tanhf(a[r] + bk);
                store_h32(smem + NODE, t2 * 63 + outb + i2, n * 16 + l15, h);
                if (root) roots[(size_t)(bid * 2 + t2) * 32 + n * 16 + l15] = h;
            }
        }
    }
    __syncthreads();
}

// log_softmax from fp32 internal LDS row -> out[g*5..]
static __device__ __forceinline__ void node_logits32(
    const char* nodebase, int R, const float* __restrict__ Wout_w,
    const float* __restrict__ Wout_b, float* __restrict__ out, size_t g)
{
    float h[32];
    #pragma unroll
    for (int c = 0; c < 8; ++c) {
        f32x4 v = *(const f32x4*)(nodebase + naddr32(R, c));
        #pragma unroll
        for (int e = 0; e < 4; ++e) h[c * 4 + e] = v[e];
    }
    float lg[OUT_N];
    #pragma unroll
    for (int o = 0; o < OUT_N; ++o) {
        const float* ww = Wout_w + o * 32;
        float s = 0.f;
        #pragma unroll
        for (int x = 0; x < 32; ++x) s = fmaf(ww[x], h[x], s);
        lg[o] = s + Wout_b[o];
    }
    float m = lg[0];
    #pragma unroll
    for (int o = 1; o < OUT_N; ++o) m = fmaxf(m, lg[o]);
    float sum = 0.f;
    #pragma unroll
    for (int o = 0; o < OUT_N; ++o) sum += expf(lg[o] - m);
    float lse = m + logf(sum);
    #pragma unroll
    for (int o = 0; o < OUT_N; ++o) out[g * OUT_N + o] = lg[o] - lse;
}

// ---------------------------------------------------------------------------
// Fused tree kernel (r13/r16-proven): block = 2 trees, 256 blocks x 512 thr,
// 1 block/CU. B staged to LDS once; all kstep reads are ds_read.
// ---------------------------------------------------------------------------
template<int BLDS>
__global__ __launch_bounds__(512, 2) void tree_kernel(
    const int* __restrict__ word_ids, const float* __restrict__ embed,
    const unsigned short* __restrict__ Bg, const float* __restrict__ bias,
    const float* __restrict__ Wout_w, const float* __restrict__ Wout_b,
    float* __restrict__ out)
{
    extern __shared__ char smem[];
    constexpr int NODE = BLDS ? B_BYTES : 0;
    constexpr int LEAF = NODE + NODE_SZ;
    const int tid = threadIdx.x, bid = blockIdx.x;
    float* roots = out + ROOTS_OFF;

    // ---- stage B into LDS (137 KB, coalesced 16B/thread) ------------------
    if constexpr (BLDS) {
        const ushort8v* src = (const ushort8v*)Bg;
        #pragma unroll
        for (int r2 = 0; r2 < 16; ++r2) {
            int idx = r2 * 512 + tid;
            *(ushort8v*)(smem + idx * 16) = src[idx];
        }
        int idx = 8192 + tid;
        if (idx < 8576) *(ushort8v*)(smem + idx * 16) = src[idx];
    }

    // ---- stage 128 leaf rows (bf16) + EXACT fp32 leaf logits --------------
    {
        int rr = tid >> 2, q4 = tid & 3;         // 4 thr/row, 8 floats each
        int leaf = bid * 128 + rr;
        int wid = word_ids[leaf];
        const f32x4* ep = (const f32x4*)(embed + (size_t)wid * 32) + q4 * 2;
        f32x4 v0 = ep[0], v1 = ep[1];
        ushort8v o;
        #pragma unroll
        for (int e = 0; e < 4; ++e) { o[e] = f2bf(v0[e]); o[4 + e] = f2bf(v1[e]); }
        *(ushort8v*)(smem + LEAF + laddr16(rr, q4)) = o;

        float lg[OUT_N];
        #pragma unroll
        for (int o5 = 0; o5 < OUT_N; ++o5) {
            const float* ww = Wout_w + o5 * 32 + q4 * 8;
            lg[o5] = ww[0]*v0[0] + ww[1]*v0[1] + ww[2]*v0[2] + ww[3]*v0[3]
                   + ww[4]*v1[0] + ww[5]*v1[1] + ww[6]*v1[2] + ww[7]*v1[3];
        }
        #pragma unroll
        for (int o5 = 0; o5 < OUT_N; ++o5) {
            lg[o5] += __shfl_xor(lg[o5], 1, 64);
            lg[o5] += __shfl_xor(lg[o5], 2, 64);
        }
        if (q4 == 0) {
            #pragma unroll
            for (int o5 = 0; o5 < OUT_N; ++o5) lg[o5] += Wout_b[o5];
            float m = lg[0];
            #pragma unroll
            for (int o5 = 1; o5 < OUT_N; ++o5) m = fmaxf(m, lg[o5]);
            float sum = 0.f;
            #pragma unroll
            for (int o5 = 0; o5 < OUT_N; ++o5) sum += expf(lg[o5] - m);
            float lse = m + logf(sum);
            #pragma unroll
            for (int o5 = 0; o5 < OUT_N; ++o5)
                out[(size_t)leaf * OUT_N + o5] = lg[o5] - lse;
        }
    }
    __syncthreads();

    // ---- 6 levels ---------------------------------------------------------
    worker_l1<BLDS>(Bg, bias, tid);
    worker_l2<BLDS>(Bg, bias, tid);
    worker_deep<BLDS>(Bg, bias, roots, bid, tid, 3, 32, 48, false);  // L3
    worker_deep<BLDS>(Bg, bias, roots, bid, tid, 2, 48, 56, false);  // L4
    worker_deep<BLDS>(Bg, bias, roots, bid, tid, 1, 56, 60, false);  // L5
    worker_deep<BLDS>(Bg, bias, roots, bid, tid, 0, 60, 62, true);   // L6

    // ---- logits for 126 internal rows (2 trees x 63) ----------------------
    if (tid < 126) {
        int tree = (tid >= 63) ? 1 : 0;
        int r = tid - 63 * tree;
        size_t tg = (size_t)bid * 2 + tree;
        int R = tree * 63 + r;
        size_t g;
        if (r < 32)      g = 32768 + tg * 32 + r;
        else if (r < 48) g = 49152 + tg * 16 + (r - 32);
        else if (r < 56) g = 57344 + tg * 8  + (r - 48);
        else if (r < 60) g = 61440 + tg * 4  + (r - 56);
        else if (r < 62) g = 63488 + tg * 2  + (r - 60);
        else             g = 64512 + tg;
        node_logits32(smem + NODE, R, Wout_w, Wout_b, out, g);
    }
}

// ---------------------------------------------------------------------------
extern "C" void kernel_launch(void* const* d_in, const int* in_sizes, int n_in,
                              void* d_out, int out_size, void* d_ws, size_t ws_size,
                              hipStream_t stream)
{
    const int*   word_ids = (const int*)  d_in[0];
    const float* embed    = (const float*)d_in[1];
    const float* V        = (const float*)d_in[2];
    const float* W        = (const float*)d_in[3];
    const float* bvec     = (const float*)d_in[4];
    const float* Wout_w   = (const float*)d_in[5];
    const float* Wout_b   = (const float*)d_in[6];
    float* out = (float*)d_out;

    unsigned short* Bfrag = (unsigned short*)d_ws;   // 137,216 B

    bprep_kernel<<<32, 256, 0, stream>>>(V, W, Bfrag);

    hipError_t e = hipFuncSetAttribute((const void*)&tree_kernel<1>,
                     hipFuncAttributeMaxDynamicSharedMemorySize, LDS_BIG);
    if (e == hipSuccess) {
        tree_kernel<1><<<256, 512, LDS_BIG, stream>>>(
            word_ids, embed, Bfrag, bvec, Wout_w, Wout_b, out);
    } else {
        tree_kernel<0><<<256, 512, LDS_SMALL, stream>>>(
            word_ids, embed, Bfrag, bvec, Wout_w, Wout_b, out);
    }
}